// Round 5
// baseline (123.986 us; speedup 1.0000x reference)
//
#include <hip/hip_runtime.h>
#include <math.h>

#define SS 8192
#define HH 2048
// W_att is (H, 2H) row-major, row stride 4096 floats; only cols [H,2H) matter.
// hidden & b_att add a constant score shift -> cancels in softmax.
//
// ws layout (floats): pp[4][2048] at ws[0..8192), scores at ws[8192..16384).
// Every ws word is written before read: no memset, no atomics, no device fences
// (cross-XCD fences cost ~100us — rounds 2/3; dispatch edges order for free).

// grid 256 = (cg 0..63, rh 0..3). Block exclusively owns cols [32cg,32cg+32)
// and rows [512rh, 512rh+512). Each 8-thread group reads a 128B-aligned
// contiguous 128B span per row -> full cacheline utilization.
__global__ void __launch_bounds__(256) colsum_kernel(
    const float* __restrict__ W,
    const float* __restrict__ w,
    float* __restrict__ pp)
{
    const int cg = blockIdx.x & 63;
    const int rh = blockIdx.x >> 6;
    const int c8 = threadIdx.x & 7;        // float4 slot within the 32 cols
    const int rg = threadIdx.x >> 3;       // 32 row-groups of 16 rows
    const int col0 = cg * 32 + c8 * 4;
    const int row0 = rh * 512 + rg * 16;

    const float* base = W + (size_t)row0 * (2 * HH) + HH + col0;
    float4 acc = make_float4(0.f, 0.f, 0.f, 0.f);
#pragma unroll
    for (int i = 0; i < 16; ++i) {
        const float wi = w[row0 + i];
        const float4 a = *(const float4*)(base + (size_t)i * (2 * HH));
        acc.x += wi * a.x; acc.y += wi * a.y;
        acc.z += wi * a.z; acc.w += wi * a.w;
    }

    __shared__ float4 lds[256];
    lds[threadIdx.x] = acc;
    __syncthreads();
    // tree over row-groups; offsets are multiples of 8 so c8 lanes never mix
    for (int off = 128; off >= 8; off >>= 1) {
        if (threadIdx.x < off) {
            float4 o = lds[threadIdx.x + off];
            float4 m = lds[threadIdx.x];
            m.x += o.x; m.y += o.y; m.z += o.z; m.w += o.w;
            lds[threadIdx.x] = m;
        }
        __syncthreads();
    }
    if (threadIdx.x < 8)
        ((float4*)(pp + (size_t)rh * HH))[cg * 8 + threadIdx.x] = lds[threadIdx.x];
}

// 2048 blocks x 256 threads: one row per wave.
// scores[row] = enc[row,:] . (pp0+pp1+pp2+pp3); pp is 32KB -> L1/L2-resident.
__global__ void __launch_bounds__(256) rowdot_kernel(
    const float* __restrict__ enc,
    const float* __restrict__ pp,
    float* __restrict__ scores)
{
    const int wave = threadIdx.x >> 6;
    const int lane = threadIdx.x & 63;
    const int row  = blockIdx.x * 4 + wave;

    const float4* p0 = (const float4*)pp;
    const float4* p1 = (const float4*)(pp + HH);
    const float4* p2 = (const float4*)(pp + 2 * HH);
    const float4* p3 = (const float4*)(pp + 3 * HH);
    const float4* e  = (const float4*)(enc + (size_t)row * HH);

    float acc = 0.0f;
#pragma unroll
    for (int i = 0; i < 8; ++i) {          // 512 float4 per row / 64 lanes
        const int idx = lane + i * 64;
        const float4 a  = e[idx];
        const float4 b0 = p0[idx];
        const float4 b1 = p1[idx];
        const float4 b2 = p2[idx];
        const float4 b3 = p3[idx];
        acc += a.x * (b0.x + b1.x + b2.x + b3.x)
             + a.y * (b0.y + b1.y + b2.y + b3.y)
             + a.z * (b0.z + b1.z + b2.z + b3.z)
             + a.w * (b0.w + b1.w + b2.w + b3.w);
    }
#pragma unroll
    for (int off = 32; off > 0; off >>= 1)
        acc += __shfl_down(acc, off);
    if (lane == 0) scores[row] = acc;
}

// single block, 1024 threads, 8 elems/thread via 2x float4; two-pass softmax.
__global__ void __launch_bounds__(1024) softmax_kernel(
    const float* __restrict__ scores,
    float* __restrict__ out)
{
    __shared__ float red[16];
    const int tid  = threadIdx.x;
    const int lane = tid & 63;
    const int wid  = tid >> 6;             // 16 waves

    const float4* s4 = (const float4*)scores;
    float4 v0 = s4[tid];
    float4 v1 = s4[tid + 1024];
    float vals[8] = { v0.x, v0.y, v0.z, v0.w, v1.x, v1.y, v1.z, v1.w };

    float m = -INFINITY;
#pragma unroll
    for (int i = 0; i < 8; ++i) m = fmaxf(m, vals[i]);
#pragma unroll
    for (int off = 1; off < 64; off <<= 1)
        m = fmaxf(m, __shfl_xor(m, off));
    if (lane == 0) red[wid] = m;
    __syncthreads();
#pragma unroll
    for (int i = 0; i < 16; ++i) m = fmaxf(m, red[i]);

    float s = 0.0f;
#pragma unroll
    for (int i = 0; i < 8; ++i) {
        vals[i] = __expf(vals[i] - m);
        s += vals[i];
    }
#pragma unroll
    for (int off = 1; off < 64; off <<= 1)
        s += __shfl_xor(s, off);
    __syncthreads();                       // done reading red (max phase)
    if (lane == 0) red[wid] = s;
    __syncthreads();
    float tot = 0.0f;
#pragma unroll
    for (int i = 0; i < 16; ++i) tot += red[i];

    const float inv = 1.0f / tot;
    float4 o0 = make_float4(vals[0] * inv, vals[1] * inv, vals[2] * inv, vals[3] * inv);
    float4 o1 = make_float4(vals[4] * inv, vals[5] * inv, vals[6] * inv, vals[7] * inv);
    float4* o4 = (float4*)out;
    o4[tid]        = o0;
    o4[tid + 1024] = o1;
}

extern "C" void kernel_launch(void* const* d_in, const int* in_sizes, int n_in,
                              void* d_out, int out_size, void* d_ws, size_t ws_size,
                              hipStream_t stream) {
    const float* enc   = (const float*)d_in[0];  // (S,1,H)
    // d_in[1] = hidden : constant score shift, cancels in softmax
    const float* W_att = (const float*)d_in[2];  // (H, 2H)
    // d_in[3] = b_att  : constant score shift, cancels
    const float* w     = (const float*)d_in[4];  // (1, H)

    float* out    = (float*)d_out;               // 8192 floats
    float* ws     = (float*)d_ws;
    float* pp     = ws;                          // 4*2048 floats
    float* scores = ws + 4 * HH;                 // 8192 floats

    hipLaunchKernelGGL(colsum_kernel,  dim3(256),  dim3(256),  0, stream, W_att, w, pp);
    hipLaunchKernelGGL(rowdot_kernel,  dim3(2048), dim3(256),  0, stream, enc, pp, scores);
    hipLaunchKernelGGL(softmax_kernel, dim3(1),    dim3(1024), 0, stream, scores, out);
}